// Round 26
// baseline (268.283 us; speedup 1.0000x reference)
//
#include <hip/hip_runtime.h>
#include <hip/hip_bf16.h>

#define NB 16
#define NT 12
#define NN 30000
#define NF 4
#define NE 960000
#define ORDER 7
#define GOUT 18
#define OUT_CH 126
#define MLP_H 64
#define HOR 12
#define NOUT 4
#define EMB 32
#define CAP 96
#define NCHUNK 64
#define CHUNK 15000            // NE / NCHUNK, divisible by 4
#define NHALF 15000            // NN / 2

typedef unsigned short u16;
typedef unsigned char u8;
typedef __attribute__((ext_vector_type(8))) _Float16 f16x8;
typedef __attribute__((ext_vector_type(4))) float f32x4;
typedef __attribute__((ext_vector_type(4))) int i32x4;

__device__ __forceinline__ float silu_f(float x) {
    return x * __builtin_amdgcn_rcpf(1.0f + __expf(-x));
}

__device__ __forceinline__ u16 f2h(float x) {
    union { _Float16 h; u16 u; } cv;
    cv.h = (_Float16)x;
    return cv.u;
}

__device__ __forceinline__ float h2f(u16 u) {
    union { u16 u2; _Float16 h; } c; c.u2 = u;
    return (float)c.h;
}

__device__ __forceinline__ float2 h2f2(unsigned v) {
    union { unsigned u; _Float16 h[2]; } c; c.u = v;
    return make_float2((float)c.h[0], (float)c.h[1]);
}

__device__ __forceinline__ unsigned packh2(float x, float y) {
    union { u16 h[2]; unsigned u; } c;
    c.h[0] = f2h(x); c.h[1] = f2h(y);
    return c.u;
}

#define WSCALE (1.0f / 65535.0f)

#define SC_BLKS 938            // ceil(NE / 1024), scatter 4 edges/thread
#define TR_BLKS 1875           // NN*NB/256
#define NPG_BLKS 469           // ceil(NN / 64)

// ---- k_cnt: LDS-histogram count + rank — ZERO global atomics -------------

__global__ __launch_bounds__(256) void k_cnt(
    const int* __restrict__ ei,
    int* __restrict__ cntRF, int* __restrict__ cntRB,
    u8* __restrict__ rnkF, u8* __restrict__ rnkB)
{
    __shared__ int hist[NHALF];   // 60000 B
    int t = threadIdx.x;
    int chunk = blockIdx.x, half = blockIdx.y, dir = blockIdx.z;
    const int* nodes = (dir == 0) ? (ei + NE) : ei;   // F counts dst, B counts src
    u8* rnk = (dir == 0) ? rnkF : rnkB;
    int* cntOut = ((dir == 0) ? cntRF : cntRB) + chunk * NN + half * NHALF;
    int base = half * NHALF;
    for (int i = t; i < NHALF; i += 256) hist[i] = 0;
    __syncthreads();
    int e0 = chunk * CHUNK;
    for (int i = t; i < CHUNK; i += 256) {
        int n = nodes[e0 + i] - base;
        if ((unsigned)n < (unsigned)NHALF) {
            int r = atomicAdd(&hist[n], 1);
            rnk[e0 + i] = (u8)r;
        }
    }
    __syncthreads();
    for (int i = t; i < NHALF; i += 256) cntOut[i] = hist[i];
}

// ---- k_misc: weight packs (incl. EwB) + transpose -------------------------

__global__ __launch_bounds__(256) void k_misc(
    const float* __restrict__ x,
    const float* __restrict__ mlp_w, const float* __restrict__ ro_w,
    const float* __restrict__ conv_w, const float* __restrict__ emb_w,
    u16* __restrict__ WmG, u16* __restrict__ RoG, u16* __restrict__ CwB,
    u16* __restrict__ EwB, u16* __restrict__ xtH)
{
    int bid = blockIdx.x;
    int t = threadIdx.x;
    if (bid == 0) {
        int j = t & 63, kb0 = t >> 6;
        #pragma unroll
        for (int kk = 0; kk < 4; ++kk) {
            int kch = kb0 + kk * 4;
            int c0 = kch * 8;
            unsigned wd[4];
            #pragma unroll
            for (int p = 0; p < 4; ++p) {
                float va = (c0 + 2*p     < 126) ? mlp_w[(c0 + 2*p    ) * 64 + j] : 0.f;
                float vb = (c0 + 2*p + 1 < 126) ? mlp_w[(c0 + 2*p + 1) * 64 + j] : 0.f;
                wd[p] = (unsigned)f2h(va) | ((unsigned)f2h(vb) << 16);
            }
            *(uint4*)&WmG[(kch * 64 + j) * 8] = make_uint4(wd[0], wd[1], wd[2], wd[3]);
        }
    } else if (bid == 1) {
        #pragma unroll
        for (int kk = 0; kk < 2; ++kk) {
            int i = t + kk * 256;
            if (i < 384) {
                int kch = i / 48, o = i - kch * 48;
                int k0 = kch * 8;
                unsigned wd[4];
                #pragma unroll
                for (int p = 0; p < 4; ++p)
                    wd[p] = (unsigned)f2h(ro_w[(k0 + 2*p) * 48 + o])
                          | ((unsigned)f2h(ro_w[(k0 + 2*p + 1) * 48 + o]) << 16);
                *(uint4*)&RoG[(kch * 48 + o) * 8] = make_uint4(wd[0], wd[1], wd[2], wd[3]);
            }
        }
    } else if (bid == 2) {
        #pragma unroll
        for (int j = 0; j < 16; ++j) {
            int idx = t + j * 256;
            int kch = idx >> 10, rem = idx & 1023, n = rem >> 3, e = rem & 7;
            int k = kch * 8 + e;
            float val = 0.f;
            if (k < 28 && n < 126) {
                int g = k >> 2, i = k & 3, q = n - g * 18;
                if (q >= 0 && q < 18) val = conv_w[(g * 4 + i) * 18 + q];
            }
            CwB[idx] = f2h(val);
        }
    } else if (bid == 3) {
        // EwB: emb_w (32x126) -> f16 MFMA B layout, K=32 x N=128 subtiled
        #pragma unroll
        for (int j = 0; j < 16; ++j) {
            int idx = t + j * 256;
            int kch = idx >> 10, rem = idx & 1023, n = rem >> 3, e = rem & 7;
            int k = kch * 8 + e;
            float val = (n < 126) ? emb_w[k * 126 + n] : 0.f;
            EwB[idx] = f2h(val);
        }
    } else {
        // transpose: x[b, T-1, n, f] -> xtH[n][b*4+f] f16
        int idx = (bid - 4) * 256 + t;   // < 480000 exactly
        int b = idx / NN;
        int n = idx - b * NN;
        float4 v = *(const float4*)&x[((((size_t)b * NT) + (NT - 1)) * NN + n) * NF];
        uint2 p;
        p.x = packh2(v.x, v.y);
        p.y = packh2(v.z, v.w);
        *(uint2*)&xtH[n * 64 + b * 4] = p;
    }
}

// ---- k_npg: npG(NN x 128) = f16( nemb(NN x 32) @ emb_w + emb_b ) via MFMA -

__global__ __launch_bounds__(256) void k_npg(
    const float* __restrict__ nemb, const float* __restrict__ emb_b,
    const u16* __restrict__ EwB, u16* __restrict__ npG)
{
    __shared__ __align__(16) u16 A_lds[64 * 32];   // K-subtiled, 4KB
    __shared__ __align__(16) float ebL[128];
    const int t = threadIdx.x;
    const int n0 = blockIdx.x * 64;
    {
        int ks = t >> 6, r = t & 63;
        int n = n0 + r;
        float4 va = make_float4(0.f, 0.f, 0.f, 0.f), vb = va;
        if (n < NN) {
            va = *(const float4*)&nemb[(size_t)n * 32 + ks * 8];
            vb = *(const float4*)&nemb[(size_t)n * 32 + ks * 8 + 4];
        }
        uint4 p;
        p.x = packh2(va.x, va.y);
        p.y = packh2(va.z, va.w);
        p.z = packh2(vb.x, vb.y);
        p.w = packh2(vb.z, vb.w);
        *(uint4*)&A_lds[(ks * 64 + r) * 8] = p;
    }
    if (t < 128) ebL[t] = (t < 126) ? emb_b[t] : 0.f;
    __syncthreads();

    const int lane = t & 63, w = t >> 6;
    const int lg = lane >> 4, lm = lane & 15;
    // transposed epilogue: thread holds row n0+w*16+lm, 4 consecutive cols
    f16x8 a = *(const f16x8*)&A_lds[(lg * 64 + w * 16 + lm) * 8];
    int n = n0 + w * 16 + lm;
    #pragma unroll
    for (int nc = 0; nc < 8; ++nc) {
        int k0 = nc * 16 + lg * 4;
        f32x4 acc = *(const f32x4*)&ebL[k0];
        f16x8 b = *(const f16x8*)&EwB[(lg * 128 + nc * 16 + lm) * 8];
        // swapped operands -> transposed tile
        acc = __builtin_amdgcn_mfma_f32_16x16x32_f16(b, a, acc, 0, 0, 0);
        if (n < NN) {
            uint2 p;
            p.x = packh2(acc[0], acc[1]);
            p.y = packh2(acc[2], acc[3]);
            *(uint2*)&npG[(size_t)n * 128 + k0] = p;
        }
    }
}

// ---- nodeprep: chunk counts -> per-chunk prefixes (in place) + total ------

__global__ __launch_bounds__(256) void k_nodeprep(
    int* __restrict__ cntRF, int* __restrict__ cntRB,
    int* __restrict__ cntAF, int* __restrict__ cntAB)
{
    int i = blockIdx.x * 256 + threadIdx.x;
    if (i >= NN) return;
    int* cntR = (blockIdx.y == 0) ? cntRF : cntRB;
    int* cntA = (blockIdx.y == 0) ? cntAF : cntAB;
    int c = 0;
    #pragma unroll 8
    for (int r = 0; r < NCHUNK; ++r) {
        int v = cntR[r * NN + i];
        cntR[r * NN + i] = c;   // chunk exclusive prefix, in place
        c += v;
    }
    cntA[i] = c;
}

// ---- scatter: atomic-free, 4B entries (u16 src | u16 fixed-point w) -------

__global__ __launch_bounds__(256) void k_scatter(
    const int* __restrict__ ei, const float* __restrict__ ew,
    const int* __restrict__ cntRF, const int* __restrict__ cntRB,
    const u8* __restrict__ rnkF, const u8* __restrict__ rnkB,
    unsigned* __restrict__ csrF, unsigned* __restrict__ csrB)
{
    int e0 = blockIdx.x * 1024 + threadIdx.x * 4;
    if (e0 >= NE) return;
    int rep = e0 / CHUNK;       // 4-aligned groups never straddle (CHUNK%4==0)
    const int* pF = cntRF + rep * NN;
    const int* pB = cntRB + rep * NN;
    if (e0 + 4 <= NE) {
        int4 s4 = *(const int4*)&ei[e0];
        int4 d4 = *(const int4*)&ei[NE + e0];
        float4 w4 = *(const float4*)&ew[e0];
        uchar4 rf = *(const uchar4*)&rnkF[e0];
        uchar4 rb = *(const uchar4*)&rnkB[e0];
        int rfv[4] = {rf.x, rf.y, rf.z, rf.w};
        int rbv[4] = {rb.x, rb.y, rb.z, rb.w};
        int ss[4] = {s4.x, s4.y, s4.z, s4.w};
        int dd[4] = {d4.x, d4.y, d4.z, d4.w};
        float wv[4] = {w4.x, w4.y, w4.z, w4.w};
        #pragma unroll
        for (int k = 0; k < 4; ++k) {
            unsigned wfix = (unsigned)(wv[k] * 65535.0f + 0.5f);
            int sF = pF[dd[k]] + rfv[k];
            int sB = pB[ss[k]] + rbv[k];
            if (sF < CAP) csrF[(size_t)dd[k] * CAP + sF] = (unsigned)ss[k] | (wfix << 16);
            if (sB < CAP) csrB[(size_t)ss[k] * CAP + sB] = (unsigned)dd[k] | (wfix << 16);
        }
    } else {
        for (int k = 0; k < 4; ++k) {
            int e = e0 + k;
            if (e >= NE) break;
            int s = ei[e], d = ei[NE + e];
            unsigned wfix = (unsigned)(ew[e] * 65535.0f + 0.5f);
            int sF = pF[d] + (int)rnkF[e];
            int sB = pB[s] + (int)rnkB[e];
            if (sF < CAP) csrF[(size_t)d * CAP + sF] = (unsigned)s | (wfix << 16);
            if (sB < CAP) csrB[(size_t)s * CAP + sB] = (unsigned)d | (wfix << 16);
        }
    }
}

// ---- one hop level: 4B CSR entries (cached: CSR ~fits L2 across levels) ---

__global__ __launch_bounds__(256) void k_hop(
    const u16* __restrict__ inF, u16* __restrict__ outF,
    const unsigned* __restrict__ csrF, const int* __restrict__ cntF,
    const u16* __restrict__ inB, u16* __restrict__ outB,
    const unsigned* __restrict__ csrB, const int* __restrict__ cntB)
{
    int lane = threadIdx.x & 63;
    int half = lane >> 5, l5 = lane & 31;
    int node = blockIdx.x * 4 + (threadIdx.x >> 6);
    if (node >= NN) return;
    const u16* in; u16* out; const unsigned* cs; const int* cntA;
    if (blockIdx.y == 0) { in = inF; out = outF; cs = csrF; cntA = cntF; }
    else                 { in = inB; out = outB; cs = csrB; cntA = cntB; }
    const unsigned* in4 = (const unsigned*)in;
    int cnt = min(cntA[node], CAP);
    const unsigned* seg = cs + (size_t)node * CAP;
    int full = cnt & ~7;
    float ax0 = 0.f, ay0 = 0.f, ax1 = 0.f, ay1 = 0.f;
    float ax2 = 0.f, ay2 = 0.f, ax3 = 0.f, ay3 = 0.f;
    float ws = 0.f;
    for (int j = 0; j < full; j += 8) {
        i32x4 q = *(const i32x4*)&seg[j + 4 * half];
        unsigned e0 = (unsigned)q.x, e1 = (unsigned)q.y;
        unsigned e2 = (unsigned)q.z, e3 = (unsigned)q.w;
        unsigned v0 = in4[(e0 & 0xFFFF) * 32 + l5];
        unsigned v1 = in4[(e1 & 0xFFFF) * 32 + l5];
        unsigned v2 = in4[(e2 & 0xFFFF) * 32 + l5];
        unsigned v3 = in4[(e3 & 0xFFFF) * 32 + l5];
        float w0 = (float)(e0 >> 16) * WSCALE;
        float w1 = (float)(e1 >> 16) * WSCALE;
        float w2 = (float)(e2 >> 16) * WSCALE;
        float w3 = (float)(e3 >> 16) * WSCALE;
        float2 f0 = h2f2(v0), f1 = h2f2(v1), f2 = h2f2(v2), f3 = h2f2(v3);
        ax0 += w0 * f0.x; ay0 += w0 * f0.y;
        ax1 += w1 * f1.x; ay1 += w1 * f1.y;
        ax2 += w2 * f2.x; ay2 += w2 * f2.y;
        ax3 += w3 * f3.x; ay3 += w3 * f3.y;
        ws += (w0 + w1) + (w2 + w3);
    }
    if (cnt & 7) {
        i32x4 q = *(const i32x4*)&seg[full + 4 * half];   // within segment
        int b0 = full + 4 * half;
        unsigned e0 = (unsigned)q.x, e1 = (unsigned)q.y;
        unsigned e2 = (unsigned)q.z, e3 = (unsigned)q.w;
        unsigned m0 = (b0     < cnt) ? e0 : 0u;
        unsigned m1 = (b0 + 1 < cnt) ? e1 : 0u;
        unsigned m2 = (b0 + 2 < cnt) ? e2 : 0u;
        unsigned m3 = (b0 + 3 < cnt) ? e3 : 0u;
        unsigned v0 = in4[(m0 & 0xFFFF) * 32 + l5];
        unsigned v1 = in4[(m1 & 0xFFFF) * 32 + l5];
        unsigned v2 = in4[(m2 & 0xFFFF) * 32 + l5];
        unsigned v3 = in4[(m3 & 0xFFFF) * 32 + l5];
        float w0 = (float)(m0 >> 16) * WSCALE;
        float w1 = (float)(m1 >> 16) * WSCALE;
        float w2 = (float)(m2 >> 16) * WSCALE;
        float w3 = (float)(m3 >> 16) * WSCALE;
        float2 f0 = h2f2(v0), f1 = h2f2(v1), f2 = h2f2(v2), f3 = h2f2(v3);
        ax0 += w0 * f0.x; ay0 += w0 * f0.y;
        ax1 += w1 * f1.x; ay1 += w1 * f1.y;
        ax2 += w2 * f2.x; ay2 += w2 * f2.y;
        ax3 += w3 * f3.x; ay3 += w3 * f3.y;
        ws += (w0 + w1) + (w2 + w3);
    }
    float tx = (ax0 + ax1) + (ax2 + ax3);
    float ty = (ay0 + ay1) + (ay2 + ay3);
    tx += __shfl_xor(tx, 32);
    ty += __shfl_xor(ty, 32);
    ws += __shfl_xor(ws, 32);
    if (half == 0) {
        float inv = 1.0f / fmaxf(ws, 1e-8f);
        ((unsigned*)out)[node * 32 + l5] = packh2(tx * inv, ty * inv);
    }
}

// ---- fused: conv(MFMA) + silu + emb + mlp(MFMA) + silu + readout(MFMA) ---
// all MFMA epilogues use swapped operands (transposed tiles) so each thread
// holds one row x 4 consecutive cols -> packed 8B/16B LDS writes

__global__ __launch_bounds__(256) void k_fused(
    const u16* __restrict__ xtH,
    const u16* __restrict__ h1, const u16* __restrict__ h2,
    const u16* __restrict__ h3, const u16* __restrict__ h4,
    const u16* __restrict__ h5, const u16* __restrict__ h6,
    const u16* __restrict__ WmG, const u16* __restrict__ RoG,
    const u16* __restrict__ CwB, const u16* __restrict__ npG,
    const float* __restrict__ conv_b,
    const float* __restrict__ mlp_b, const float* __restrict__ ro_b,
    float* __restrict__ out)
{
    __shared__ __align__(16) u16 HtB[8192];      // 16KB; aliased as C2L (f32) in stage 3
    __shared__ __align__(16) u16 C1B[4096];      // 8KB; aliased as A_lds (4KB) in stage 0/1
    __shared__ __align__(16) float cbL[128];
    __shared__ __align__(16) float mbL[64];
    __shared__ __align__(16) float rbL[48];

    u16* A_lds = C1B;   // [(k>>3)*64 + r]*8 + (k&7), K=32 (28 used), 64 rows = 4KB

    const int t = threadIdx.x;
    const int n0 = blockIdx.x * 4;
    const int lane = t & 63;
    const int w = t >> 6;
    const int lg = lane >> 4, lm = lane & 15;

    // ---- stage 0: row-assembled staging, 1 ds_write_b128 per thread ----
    {
        int ks = t >> 6, r = t & 63;        // wave ks stages K-subtile ks
        uint2 a, b;
        if (ks == 0) {
            a = *(const uint2*)&xtH[n0 * 64 + r * 4];
            b = *(const uint2*)&h1[n0 * 64 + r * 4];
        } else if (ks == 1) {
            a = *(const uint2*)&h2[n0 * 64 + r * 4];
            b = *(const uint2*)&h3[n0 * 64 + r * 4];
        } else if (ks == 2) {
            a = *(const uint2*)&h4[n0 * 64 + r * 4];
            b = *(const uint2*)&h5[n0 * 64 + r * 4];
        } else {
            a = *(const uint2*)&h6[n0 * 64 + r * 4];
            b = make_uint2(0u, 0u);         // pad k=28..31
        }
        *(uint4*)&A_lds[(ks * 64 + r) * 8] = make_uint4(a.x, a.y, b.x, b.y);
    }
    if (t < 128) cbL[t] = (t < 126) ? conv_b[t] : 0.f;
    if (t < 64) mbL[t] = mlp_b[t];
    if (t < 48) rbL[t] = ro_b[t];
    __syncthreads();

    // ---- stage 1: H(64x128) = silu(A(64x32) @ Cw(32x128) + cb) + np ----
    // transposed: thread holds H[row = w*16+lm][k0 .. k0+3]
    {
        f16x8 a = *(const f16x8*)&A_lds[(lg * 64 + w * 16 + lm) * 8];
        const int row = w * 16 + lm;
        const u16* npRow = npG + (size_t)(n0 + w) * 128;
        #pragma unroll
        for (int nc = 0; nc < 8; ++nc) {
            int k0 = nc * 16 + lg * 4;
            f32x4 acc = *(const f32x4*)&cbL[k0];
            f16x8 b = *(const f16x8*)&CwB[(lg * 128 + nc * 16 + lm) * 8];
            acc = __builtin_amdgcn_mfma_f32_16x16x32_f16(b, a, acc, 0, 0, 0);
            uint2 npp = *(const uint2*)&npRow[k0];
            float2 np0 = h2f2(npp.x), np1 = h2f2(npp.y);
            uint2 pw;
            pw.x = packh2(silu_f(acc[0]) + np0.x, silu_f(acc[1]) + np0.y);
            pw.y = packh2(silu_f(acc[2]) + np1.x, silu_f(acc[3]) + np1.y);
            *(uint2*)&HtB[((k0 >> 3) * 64 + row) * 8 + (k0 & 7)] = pw;
        }
    }
    __syncthreads();

    // ---- stage 2: C1(64x64) = silu(H(64x128) @ Wm(128x64) + mb) -> C1B f16
    // transposed: thread holds C1[row][4 consecutive cols]
    {
        const int wr = w >> 1, wc = w & 1;
        int c0 = wc * 32 + lg * 4;          // low col group
        int c1 = c0 + 16;                    // high col group
        f32x4 acc00 = *(const f32x4*)&mbL[c0];
        f32x4 acc01 = *(const f32x4*)&mbL[c1];
        f32x4 acc10 = acc00;
        f32x4 acc11 = acc01;
        #pragma unroll
        for (int kc = 0; kc < 4; ++kc) {
            const int kb = (kc * 4 + lg) * 64;
            f16x8 a0 = *(const f16x8*)&HtB[(kb + wr * 32 + lm) * 8];
            f16x8 a1 = *(const f16x8*)&HtB[(kb + wr * 32 + 16 + lm) * 8];
            f16x8 b0 = *(const f16x8*)&WmG[(kb + wc * 32 + lm) * 8];
            f16x8 b1 = *(const f16x8*)&WmG[(kb + wc * 32 + 16 + lm) * 8];
            acc00 = __builtin_amdgcn_mfma_f32_16x16x32_f16(b0, a0, acc00, 0, 0, 0);
            acc01 = __builtin_amdgcn_mfma_f32_16x16x32_f16(b1, a0, acc01, 0, 0, 0);
            acc10 = __builtin_amdgcn_mfma_f32_16x16x32_f16(b0, a1, acc10, 0, 0, 0);
            acc11 = __builtin_amdgcn_mfma_f32_16x16x32_f16(b1, a1, acc11, 0, 0, 0);
        }
        // rows: low = wr*32+lm, high = +16; A_lds (alias C1B) fully consumed
        int r0 = wr * 32 + lm, r1 = r0 + 16;
        uint2 pw;
        pw.x = packh2(silu_f(acc00[0]), silu_f(acc00[1]));
        pw.y = packh2(silu_f(acc00[2]), silu_f(acc00[3]));
        *(uint2*)&C1B[((c0 >> 3) * 64 + r0) * 8 + (c0 & 7)] = pw;
        pw.x = packh2(silu_f(acc01[0]), silu_f(acc01[1]));
        pw.y = packh2(silu_f(acc01[2]), silu_f(acc01[3]));
        *(uint2*)&C1B[((c1 >> 3) * 64 + r0) * 8 + (c1 & 7)] = pw;
        pw.x = packh2(silu_f(acc10[0]), silu_f(acc10[1]));
        pw.y = packh2(silu_f(acc10[2]), silu_f(acc10[3]));
        *(uint2*)&C1B[((c0 >> 3) * 64 + r1) * 8 + (c0 & 7)] = pw;
        pw.x = packh2(silu_f(acc11[0]), silu_f(acc11[1]));
        pw.y = packh2(silu_f(acc11[2]), silu_f(acc11[3]));
        *(uint2*)&C1B[((c1 >> 3) * 64 + r1) * 8 + (c1 & 7)] = pw;
    }
    __syncthreads();

    // ---- stage 3: C2(64x48) = C1(64x64) @ Ro(64x48) + rb ----
    // transposed: thread holds C2[row = w*16+lm][4 consecutive cols] x3
    {
        const int rt3 = w * 16;
        int o0 = lg * 4;
        f32x4 c0 = *(const f32x4*)&rbL[o0];
        f32x4 c1 = *(const f32x4*)&rbL[16 + o0];
        f32x4 c2 = *(const f32x4*)&rbL[32 + o0];
        #pragma unroll
        for (int kc = 0; kc < 2; ++kc) {
            const int kb = kc * 4 + lg;
            f16x8 a  = *(const f16x8*)&C1B[(kb * 64 + rt3 + lm) * 8];
            f16x8 b0 = *(const f16x8*)&RoG[(kb * 48 + lm) * 8];
            f16x8 b1 = *(const f16x8*)&RoG[(kb * 48 + 16 + lm) * 8];
            f16x8 b2 = *(const f16x8*)&RoG[(kb * 48 + 32 + lm) * 8];
            c0 = __builtin_amdgcn_mfma_f32_16x16x32_f16(b0, a, c0, 0, 0, 0);
            c1 = __builtin_amdgcn_mfma_f32_16x16x32_f16(b1, a, c1, 0, 0, 0);
            c2 = __builtin_amdgcn_mfma_f32_16x16x32_f16(b2, a, c2, 0, 0, 0);
        }
        float* C2L = (float*)HtB;   // HtB dead after stage 2
        int row = rt3 + lm;
        *(f32x4*)&C2L[row * 52 + o0]      = c0;
        *(f32x4*)&C2L[row * 52 + 16 + o0] = c1;
        *(f32x4*)&C2L[row * 52 + 32 + o0] = c2;
    }
    __syncthreads();

    // ---- output: out[b][hor][n][o] ----
    if (t < 192) {
        int b = t / 12, hor = t - b * 12;
        const float* C2L = (const float*)HtB;
        #pragma unroll
        for (int nl2 = 0; nl2 < 4; ++nl2) {
            f32x4 v = *(const f32x4*)&C2L[(nl2 * 16 + b) * 52 + hor * 4];
            *(f32x4*)&out[(((size_t)b * 12 + hor) * 30000 + n0 + nl2) * 4] = v;
        }
    }
}

// ---- launch --------------------------------------------------------------

extern "C" void kernel_launch(void* const* d_in, const int* in_sizes, int n_in,
                              void* d_out, int out_size, void* d_ws, size_t ws_size,
                              hipStream_t stream)
{
    const float* x      = (const float*)d_in[0];
    const int*   ei     = (const int*)d_in[1];
    const float* ew     = (const float*)d_in[2];
    const float* conv_w = (const float*)d_in[3];
    const float* conv_b = (const float*)d_in[4];
    const float* nemb   = (const float*)d_in[5];
    const float* emb_w  = (const float*)d_in[6];
    const float* emb_b  = (const float*)d_in[7];
    const float* mlp_w  = (const float*)d_in[8];
    const float* mlp_b  = (const float*)d_in[9];
    const float* ro_w   = (const float*)d_in[10];
    const float* ro_b   = (const float*)d_in[11];
    float* out = (float*)d_out;

    char* ws = (char*)d_ws;
    size_t off = 0;
    auto alloc = [&](size_t bytes) -> char* {
        char* p = ws + off;
        off += (bytes + 255) & ~(size_t)255;
        return p;
    };

    int* cntRF  = (int*)alloc((size_t)NCHUNK * NN * 4);   // 7.68 MB, fully written
    int* cntRB  = (int*)alloc((size_t)NCHUNK * NN * 4);
    int* cntAF  = (int*)alloc(NN * 4);
    int* cntAB  = (int*)alloc(NN * 4);
    u8* rnkF    = (u8*)alloc(NE);
    u8* rnkB    = (u8*)alloc(NE);
    unsigned* csrF = (unsigned*)alloc((size_t)NN * CAP * 4);   // 11.52 MB
    unsigned* csrB = (unsigned*)alloc((size_t)NN * CAP * 4);
    u16* xtH    = (u16*)alloc((size_t)NN * 64 * 2);
    u16* hbuf[6];
    for (int i = 0; i < 6; ++i) hbuf[i] = (u16*)alloc((size_t)NN * 64 * 2);
    u16* npG    = (u16*)alloc((size_t)NN * 128 * 2);
    u16* WmG    = (u16*)alloc(8192 * 2);
    u16* RoG    = (u16*)alloc(3072 * 2);
    u16* CwB    = (u16*)alloc(4096 * 2);
    u16* EwB    = (u16*)alloc(4096 * 2);

    // no memset needed: cntR / rnk fully written by k_cnt every call

    k_cnt<<<dim3(NCHUNK, 2, 2), 256, 0, stream>>>(ei, cntRF, cntRB, rnkF, rnkB);
    k_misc<<<4 + TR_BLKS, 256, 0, stream>>>(
        x, mlp_w, ro_w, conv_w, emb_w,
        WmG, RoG, CwB, EwB, xtH);
    k_npg<<<NPG_BLKS, 256, 0, stream>>>(nemb, emb_b, EwB, npG);
    k_nodeprep<<<dim3((NN + 255) / 256, 2), 256, 0, stream>>>(
        cntRF, cntRB, cntAF, cntAB);
    k_scatter<<<SC_BLKS, 256, 0, stream>>>(ei, ew, cntRF, cntRB,
                                           rnkF, rnkB, csrF, csrB);

    dim3 nodeGrid((NN + 3) / 4, 2);
    k_hop<<<nodeGrid, 256, 0, stream>>>(xtH, hbuf[0], csrF, cntAF,
                                        xtH, hbuf[3], csrB, cntAB);
    k_hop<<<nodeGrid, 256, 0, stream>>>(hbuf[0], hbuf[1], csrF, cntAF,
                                        hbuf[3], hbuf[4], csrB, cntAB);
    k_hop<<<nodeGrid, 256, 0, stream>>>(hbuf[1], hbuf[2], csrF, cntAF,
                                        hbuf[4], hbuf[5], csrB, cntAB);

    k_fused<<<NN / 4, 256, 0, stream>>>(xtH, hbuf[0], hbuf[1], hbuf[2],
                                        hbuf[3], hbuf[4], hbuf[5],
                                        WmG, RoG, CwB, npG,
                                        conv_b, mlp_b, ro_b, out);
}